// Round 4
// baseline (296.109 us; speedup 1.0000x reference)
//
#include <hip/hip_runtime.h>
#include <math.h>

static constexpr int T_TOK = 16384;   // 4*4096 tokens
static constexpr int E     = 256;     // experts
static constexpr int H     = 2048;    // hidden dim

// ---------------------------------------------------------------------------
// Kernel 0: W[e][k] -> Bt[k][e]  (2 MB) so the GEMM can scalar-load 8
// consecutive experts per k as one wave-uniform 32B block.
// ---------------------------------------------------------------------------
__global__ __launch_bounds__(256) void transpose_w(const float* __restrict__ W,
                                                   float* __restrict__ Bt) {
    __shared__ float tile[32][33];
    const int kb = blockIdx.x * 32;
    const int eb = blockIdx.y * 32;
    const int tx = threadIdx.x & 31;
    const int ty = threadIdx.x >> 5;          // 0..7
#pragma unroll
    for (int i = 0; i < 4; ++i)
        tile[ty + 8 * i][tx] = W[(size_t)(eb + ty + 8 * i) * H + kb + tx];
    __syncthreads();
#pragma unroll
    for (int i = 0; i < 4; ++i)
        Bt[(size_t)(kb + ty + 8 * i) * E + eb + tx] = tile[tx][ty + 8 * i];
}

// ---------------------------------------------------------------------------
// Kernel 1: partial logits, split-K, SGPR-broadcast B.
// Block = 512 threads = 8 waves. Each wave owns 8 experts (wave-uniform ->
// B comes from scalar loads, zero LDS/VGPR cost). Lanes own 8 tokens each
// (two contiguous groups of 4) -> linear conflict-free ds_read_b128 of A.
// Numerics: f32 slab over BK=64, flushed into f32 major (error ~1e-7 total
// after f64 combine of split-K partials in the route kernel).
// ---------------------------------------------------------------------------
__global__ __launch_bounds__(512, 2) void gemm_logits(const float* __restrict__ X,
                                                      const float* __restrict__ Bt,
                                                      float* __restrict__ Cp,
                                                      int klen) {
    __shared__ float At[16][512];             // 32 KB, [k][token-slot]

    const int tid  = threadIdx.x;
    const int lane = tid & 63;
    const int wv   = __builtin_amdgcn_readfirstlane(tid >> 6);  // 0..7
    const int bn   = blockIdx.x;              // expert block (64 wide)
    const int bm   = blockIdx.y;              // token block (512 tall)
    const int kz   = blockIdx.z;              // split-K chunk
    const int kbase = kz * klen;
    const int TB   = bm * 512;
    const int e0   = bn * 64 + wv * 8;        // wave-uniform expert base
    const int l4   = lane * 4;

    // staging: thread t stages token slot t's 16 k-values per kt
    const float* Xrow = X + (size_t)(TB + tid) * H + kbase;
    float4 st0 = *(const float4*)(Xrow + 0);
    float4 st1 = *(const float4*)(Xrow + 4);
    float4 st2 = *(const float4*)(Xrow + 8);
    float4 st3 = *(const float4*)(Xrow + 12);

    float pm[8][8];   // slab accumulator (BK=64)
    float am[8][8];   // major accumulator
#pragma unroll
    for (int m = 0; m < 8; ++m)
#pragma unroll
        for (int n = 0; n < 8; ++n) { pm[m][n] = 0.f; am[m][n] = 0.f; }

    const int NK = klen / 16;
    for (int kt = 0; kt < NK; ++kt) {
        __syncthreads();                      // previous reads done
        At[ 0][tid] = st0.x; At[ 1][tid] = st0.y; At[ 2][tid] = st0.z; At[ 3][tid] = st0.w;
        At[ 4][tid] = st1.x; At[ 5][tid] = st1.y; At[ 6][tid] = st1.z; At[ 7][tid] = st1.w;
        At[ 8][tid] = st2.x; At[ 9][tid] = st2.y; At[10][tid] = st2.z; At[11][tid] = st2.w;
        At[12][tid] = st3.x; At[13][tid] = st3.y; At[14][tid] = st3.z; At[15][tid] = st3.w;
        __syncthreads();

        if (kt + 1 < NK) {                    // prefetch next tile (hides under FMAs)
            const float* xn = Xrow + (kt + 1) * 16;
            st0 = *(const float4*)(xn + 0);
            st1 = *(const float4*)(xn + 4);
            st2 = *(const float4*)(xn + 8);
            st3 = *(const float4*)(xn + 12);
        }

        const float* bp = Bt + (size_t)(kbase + kt * 16) * E + e0;  // uniform
#pragma unroll
        for (int kk = 0; kk < 16; ++kk) {
            float4 a0 = *(const float4*)&At[kk][l4];        // tokens l4..l4+3
            float4 a1 = *(const float4*)&At[kk][256 + l4];  // tokens 256+l4..
            float b[8];
#pragma unroll
            for (int n = 0; n < 8; ++n) b[n] = bp[(size_t)kk * E + n];  // s_load
            float a[8] = {a0.x, a0.y, a0.z, a0.w, a1.x, a1.y, a1.z, a1.w};
#pragma unroll
            for (int m = 0; m < 8; ++m)
#pragma unroll
                for (int n = 0; n < 8; ++n)
                    pm[m][n] = fmaf(a[m], b[n], pm[m][n]);
        }

        if ((kt & 3) == 3) {                  // flush slab -> major every BK=64
#pragma unroll
            for (int m = 0; m < 8; ++m)
#pragma unroll
                for (int n = 0; n < 8; ++n) { am[m][n] += pm[m][n]; pm[m][n] = 0.f; }
        }
    }

    float* Cz = Cp + (size_t)kz * T_TOK * E;
#pragma unroll
    for (int m = 0; m < 8; ++m) {
        const int tok = TB + ((m < 4) ? (l4 + m) : (256 + l4 + (m - 4)));
        float4 v0 = make_float4(am[m][0], am[m][1], am[m][2], am[m][3]);
        float4 v1 = make_float4(am[m][4], am[m][5], am[m][6], am[m][7]);
        *(float4*)&Cz[(size_t)tok * E + e0]     = v0;
        *(float4*)&Cz[(size_t)tok * E + e0 + 4] = v1;
    }
}

// ---------------------------------------------------------------------------
// Kernel 2: fused split-K reduce + routing (proven in round 3). 16 lanes per
// token, 16 experts per lane, all in registers. Correctly-rounded double
// sigmoid; f32 comparisons matching numpy; exact lax.top_k tie-breaks.
// ---------------------------------------------------------------------------
__global__ __launch_bounds__(256) void route_kernel(const float* __restrict__ P,
                                                    const float* __restrict__ bias,
                                                    float* __restrict__ out,
                                                    int nsplit) {
    const int sub = threadIdx.x & 15;                    // expert chunk 0..15
    const int tok = blockIdx.x * 16 + (threadIdx.x >> 4);
    const int ebase = sub * 16;

    double accd[16];
#pragma unroll
    for (int i = 0; i < 16; ++i) accd[i] = 0.0;
    for (int s = 0; s < nsplit; ++s) {
        const float* base = P + (size_t)s * T_TOK * E + (size_t)tok * E + ebase;
#pragma unroll
        for (int v = 0; v < 4; ++v) {
            float4 f = *(const float4*)(base + v * 4);
            accd[v * 4 + 0] += (double)f.x; accd[v * 4 + 1] += (double)f.y;
            accd[v * 4 + 2] += (double)f.z; accd[v * 4 + 3] += (double)f.w;
        }
    }

    float us[16], sc[16];
#pragma unroll
    for (int i = 0; i < 16; ++i) {
        float lg = (float)accd[i];
        double s = 1.0 / (1.0 + exp(-(double)lg));
        us[i] = (float)s;
        sc[i] = us[i] + bias[ebase + i];
    }

    float m1 = -1e30f, m2 = -1e30f;
#pragma unroll
    for (int i = 0; i < 16; ++i) {
        float s = sc[i];
        if (s > m1)      { m2 = m1; m1 = s; }
        else if (s > m2) { m2 = s; }
    }
    float pm1 = __shfl_xor(m1, 1, 16);
    float pm2 = __shfl_xor(m2, 1, 16);
    float gsum = (m1 >= pm1) ? (m1 + fmaxf(m2, pm1)) : (pm1 + fmaxf(pm2, m1));

    const int g = sub >> 1;
    int rank = 0;
#pragma unroll
    for (int h = 0; h < 8; ++h) {
        float gh = __shfl(gsum, h * 2, 16);
        if (h != g && (gh > gsum || (gh == gsum && h < g))) ++rank;
    }
    const bool sel = (rank < 4);

    unsigned used = 0;
    float myoi = 0.f, myow = 0.f;
    float wsum = 0.f;
#pragma unroll
    for (int p = 0; p < 8; ++p) {
        float bv = -1e30f; int bi = 0x7fff; float bu = 0.f;
#pragma unroll
        for (int i = 0; i < 16; ++i) {
            float v = ((used >> i) & 1u) ? -1e30f : (sel ? sc[i] : 0.0f);
            if (v > bv || (v == bv && (ebase + i) < bi)) {
                bv = v; bi = ebase + i; bu = us[i];
            }
        }
#pragma unroll
        for (int d = 1; d < 16; d <<= 1) {
            float ov = __shfl_xor(bv, d, 16);
            int   oi = __shfl_xor(bi, d, 16);
            float ou = __shfl_xor(bu, d, 16);
            if (ov > bv || (ov == bv && oi < bi)) { bv = ov; bi = oi; bu = ou; }
        }
        if ((bi >> 4) == sub) used |= 1u << (bi & 15);
        if (sub == p) { myoi = (float)bi; myow = bu; }
        wsum += bu;
    }

    const float scale = 2.5f / (wsum + 1e-20f);
    if (sub < 8) {
        out[(size_t)tok * 8 + sub] = myoi;
        out[(size_t)T_TOK * 8 + (size_t)tok * 8 + sub] = myow * scale;
    }
}

// ---------------------------------------------------------------------------
extern "C" void kernel_launch(void* const* d_in, const int* in_sizes, int n_in,
                              void* d_out, int out_size, void* d_ws, size_t ws_size,
                              hipStream_t stream) {
    const float* X = (const float*)d_in[0];   // [4,4096,2048] fp32
    const float* W = (const float*)d_in[1];   // [256,2048]   fp32
    const float* B = (const float*)d_in[2];   // [256]        fp32
    float* out     = (float*)d_out;

    const size_t btB    = (size_t)H * E * sizeof(float);        // 2 MB
    const size_t chunkB = (size_t)T_TOK * E * sizeof(float);    // 16 MB
    float* Bt   = (float*)d_ws;
    float* part = (float*)((char*)d_ws + btB);

    int nsplit = 1;
    if (ws_size >= btB + 4 * chunkB)      nsplit = 4;
    else if (ws_size >= btB + 2 * chunkB) nsplit = 2;
    const int klen = H / nsplit;

    dim3 tg(H / 32, E / 32);                  // (64, 8)
    transpose_w<<<tg, 256, 0, stream>>>(W, Bt);

    dim3 gg(E / 64, T_TOK / 512, nsplit);     // (4, 32, nsplit)
    gemm_logits<<<gg, 512, 0, stream>>>(X, Bt, part, klen);

    route_kernel<<<T_TOK / 16, 256, 0, stream>>>(part, B, out, nsplit);
}

// Round 5
// 130.247 us; speedup vs baseline: 2.2734x; 2.2734x over previous
//
#include <hip/hip_runtime.h>
#include <hip/hip_bf16.h>
#include <math.h>

static constexpr int T_TOK = 16384;   // 4*4096 tokens
static constexpr int E     = 256;     // experts
static constexpr int H     = 2048;    // hidden dim

typedef __attribute__((ext_vector_type(8))) short          bf16x8;
typedef __attribute__((ext_vector_type(8))) unsigned short u16x8;
typedef __attribute__((ext_vector_type(4))) float          f32x4;

// Exact 3-way bf16 split: x == h + m + l (24 mantissa bits, RN at each stage).
__device__ __forceinline__ void split3(float x, unsigned short& h,
                                       unsigned short& m, unsigned short& l) {
    __hip_bfloat16 bh = __float2bfloat16(x);
    float fh = __bfloat162float(bh);
    float r1 = x - fh;                      // exact (Sterbenz-style)
    __hip_bfloat16 bm = __float2bfloat16(r1);
    float fm = __bfloat162float(bm);
    float r2 = r1 - fm;                     // exact
    __hip_bfloat16 bl = __float2bfloat16(r2);
    h = *(unsigned short*)&bh; m = *(unsigned short*)&bm; l = *(unsigned short*)&bl;
}

// ---------------------------------------------------------------------------
// Kernel 0: split W [256][2048] fp32 into three bf16 planes (same layout).
// ---------------------------------------------------------------------------
__global__ __launch_bounds__(256) void prep_w(const float* __restrict__ W,
                                              unsigned short* __restrict__ Wh,
                                              unsigned short* __restrict__ Wm,
                                              unsigned short* __restrict__ Wl) {
    const int i = (blockIdx.x * 256 + threadIdx.x) * 4;
    float4 x = *(const float4*)(W + i);
    unsigned short h[4], m[4], l[4];
    split3(x.x, h[0], m[0], l[0]);
    split3(x.y, h[1], m[1], l[1]);
    split3(x.z, h[2], m[2], l[2]);
    split3(x.w, h[3], m[3], l[3]);
#pragma unroll
    for (int q = 0; q < 4; ++q) { Wh[i+q] = h[q]; Wm[i+q] = m[q]; Wl[i+q] = l[q]; }
}

// ---------------------------------------------------------------------------
// Kernel 1: partial logits via bf16x3 MFMA (6 passes: hh,hm,mh,mm,hl,lh).
// Block 128 tokens x 128 experts, 4 waves (2Mx2N), wave tile 64x64 = 4x4
// frags of mfma_f32_16x16x32_bf16. BK=32. Split-K over blockIdx.z.
// LDS planes padded to 40 bf16/row: frag ds_read_b128 is 2-way (free).
// ---------------------------------------------------------------------------
__global__ __launch_bounds__(256, 2) void gemm_logits(
        const float* __restrict__ X,
        const unsigned short* __restrict__ Wh,
        const unsigned short* __restrict__ Wm,
        const unsigned short* __restrict__ Wl,
        float* __restrict__ Cp, int klen) {
    __shared__ __align__(16) unsigned short As[3][128][40];
    __shared__ __align__(16) unsigned short Bs[3][128][40];

    const int tid  = threadIdx.x;
    const int lane = tid & 63;
    const int wid  = tid >> 6;            // 0..3
    const int wm   = wid >> 1, wn = wid & 1;
    const int bn   = blockIdx.x;          // 0..1  expert block (128)
    const int bm   = blockIdx.y;          // 0..127 token block (128)
    const int kz   = blockIdx.z;
    const int kbase = kz * klen;
    const int TB   = bm * 128;
    const int eb   = bn * 128;

    // staging coords: each thread owns row=tid>>1, k-half=(tid&1)*16
    const int srow  = tid >> 1;
    const int halfk = (tid & 1) * 16;

    const float*          Xp  = X  + (size_t)(TB + srow) * H + kbase + halfk;
    const unsigned short* Whp = Wh + (size_t)(eb + srow) * H + kbase + halfk;
    const unsigned short* Wmp = Wm + (size_t)(eb + srow) * H + kbase + halfk;
    const unsigned short* Wlp = Wl + (size_t)(eb + srow) * H + kbase + halfk;

    // frag coords
    const int frow = lane & 15;
    const int fk   = (lane >> 4) * 8;

    float4 ax0, ax1, ax2, ax3;
    int4   bxh0, bxh1, bxm0, bxm1, bxl0, bxl1;

    // prologue loads (step 0)
    ax0 = *(const float4*)(Xp + 0);  ax1 = *(const float4*)(Xp + 4);
    ax2 = *(const float4*)(Xp + 8);  ax3 = *(const float4*)(Xp + 12);
    bxh0 = *(const int4*)(Whp);      bxh1 = *(const int4*)(Whp + 8);
    bxm0 = *(const int4*)(Wmp);      bxm1 = *(const int4*)(Wmp + 8);
    bxl0 = *(const int4*)(Wlp);      bxl1 = *(const int4*)(Wlp + 8);

    f32x4 acc[4][4];
#pragma unroll
    for (int i = 0; i < 4; ++i)
#pragma unroll
        for (int j = 0; j < 4; ++j) acc[i][j] = (f32x4){0.f, 0.f, 0.f, 0.f};

    const int NK = klen / 32;
    for (int kt = 0; kt < NK; ++kt) {
        __syncthreads();   // prior step's frag reads done

        // ---- write A planes (convert fp32 -> h,m,l bf16)
        {
            float xv[16] = {ax0.x, ax0.y, ax0.z, ax0.w, ax1.x, ax1.y, ax1.z, ax1.w,
                            ax2.x, ax2.y, ax2.z, ax2.w, ax3.x, ax3.y, ax3.z, ax3.w};
            u16x8 vh0, vh1, vm0, vm1, vl0, vl1;
#pragma unroll
            for (int t = 0; t < 8; ++t) {
                unsigned short h, m, l;
                split3(xv[t], h, m, l);
                vh0[t] = h; vm0[t] = m; vl0[t] = l;
            }
#pragma unroll
            for (int t = 0; t < 8; ++t) {
                unsigned short h, m, l;
                split3(xv[8 + t], h, m, l);
                vh1[t] = h; vm1[t] = m; vl1[t] = l;
            }
            *(u16x8*)&As[0][srow][halfk]     = vh0;
            *(u16x8*)&As[0][srow][halfk + 8] = vh1;
            *(u16x8*)&As[1][srow][halfk]     = vm0;
            *(u16x8*)&As[1][srow][halfk + 8] = vm1;
            *(u16x8*)&As[2][srow][halfk]     = vl0;
            *(u16x8*)&As[2][srow][halfk + 8] = vl1;
        }
        // ---- write B planes (already bf16)
        *(int4*)&Bs[0][srow][halfk]     = bxh0;
        *(int4*)&Bs[0][srow][halfk + 8] = bxh1;
        *(int4*)&Bs[1][srow][halfk]     = bxm0;
        *(int4*)&Bs[1][srow][halfk + 8] = bxm1;
        *(int4*)&Bs[2][srow][halfk]     = bxl0;
        *(int4*)&Bs[2][srow][halfk + 8] = bxl1;

        __syncthreads();

        // ---- prefetch next step's staging (hides under MFMAs)
        if (kt + 1 < NK) {
            const float*          xn = Xp  + (kt + 1) * 32;
            const unsigned short* hn = Whp + (kt + 1) * 32;
            const unsigned short* mn = Wmp + (kt + 1) * 32;
            const unsigned short* ln = Wlp + (kt + 1) * 32;
            ax0 = *(const float4*)(xn + 0);  ax1 = *(const float4*)(xn + 4);
            ax2 = *(const float4*)(xn + 8);  ax3 = *(const float4*)(xn + 12);
            bxh0 = *(const int4*)(hn);       bxh1 = *(const int4*)(hn + 8);
            bxm0 = *(const int4*)(mn);       bxm1 = *(const int4*)(mn + 8);
            bxl0 = *(const int4*)(ln);       bxl1 = *(const int4*)(ln + 8);
        }

        // ---- load all frags (24 x ds_read_b128), then 96 MFMAs
        bf16x8 af[3][4], bf[3][4];
#pragma unroll
        for (int s = 0; s < 3; ++s)
#pragma unroll
            for (int i = 0; i < 4; ++i) {
                af[s][i] = *(const bf16x8*)&As[s][wm * 64 + i * 16 + frow][fk];
                bf[s][i] = *(const bf16x8*)&Bs[s][wn * 64 + i * 16 + frow][fk];
            }

        // passes: (h,h) (h,m) (m,h) (m,m) (h,l) (l,h)
#pragma unroll
        for (int p = 0; p < 6; ++p) {
            const int SA[6] = {0, 0, 1, 1, 0, 2};
            const int SB[6] = {0, 1, 0, 1, 2, 0};
            const int sa = SA[p], sb = SB[p];
#pragma unroll
            for (int i = 0; i < 4; ++i)
#pragma unroll
                for (int j = 0; j < 4; ++j)
                    acc[i][j] = __builtin_amdgcn_mfma_f32_16x16x32_bf16(
                        af[sa][i], bf[sb][j], acc[i][j], 0, 0, 0);
        }
    }

    // ---- epilogue: D layout col=lane&15, row=(lane>>4)*4+r
    float* Cz = Cp + (size_t)kz * T_TOK * E;
    const int rbase = (lane >> 4) * 4;
#pragma unroll
    for (int i = 0; i < 4; ++i)
#pragma unroll
        for (int j = 0; j < 4; ++j) {
            const int ecol = eb + wn * 64 + j * 16 + frow;
#pragma unroll
            for (int r = 0; r < 4; ++r) {
                const int tok = TB + wm * 64 + i * 16 + rbase + r;
                Cz[(size_t)tok * E + ecol] = acc[i][j][r];
            }
        }
}

// ---------------------------------------------------------------------------
// Kernel 2: fused split-K reduce + routing (proven). 16 lanes/token, 16
// experts/lane, all in registers; exact lax.top_k tie-breaks.
// ---------------------------------------------------------------------------
__global__ __launch_bounds__(256) void route_kernel(const float* __restrict__ P,
                                                    const float* __restrict__ bias,
                                                    float* __restrict__ out,
                                                    int nsplit) {
    const int sub = threadIdx.x & 15;
    const int tok = blockIdx.x * 16 + (threadIdx.x >> 4);
    const int ebase = sub * 16;

    double accd[16];
#pragma unroll
    for (int i = 0; i < 16; ++i) accd[i] = 0.0;
    for (int s = 0; s < nsplit; ++s) {
        const float* base = P + (size_t)s * T_TOK * E + (size_t)tok * E + ebase;
#pragma unroll
        for (int v = 0; v < 4; ++v) {
            float4 f = *(const float4*)(base + v * 4);
            accd[v * 4 + 0] += (double)f.x; accd[v * 4 + 1] += (double)f.y;
            accd[v * 4 + 2] += (double)f.z; accd[v * 4 + 3] += (double)f.w;
        }
    }

    float us[16], sc[16];
#pragma unroll
    for (int i = 0; i < 16; ++i) {
        float lg = (float)accd[i];
        double s = 1.0 / (1.0 + exp(-(double)lg));
        us[i] = (float)s;
        sc[i] = us[i] + bias[ebase + i];
    }

    float m1 = -1e30f, m2 = -1e30f;
#pragma unroll
    for (int i = 0; i < 16; ++i) {
        float s = sc[i];
        if (s > m1)      { m2 = m1; m1 = s; }
        else if (s > m2) { m2 = s; }
    }
    float pm1 = __shfl_xor(m1, 1, 16);
    float pm2 = __shfl_xor(m2, 1, 16);
    float gsum = (m1 >= pm1) ? (m1 + fmaxf(m2, pm1)) : (pm1 + fmaxf(pm2, m1));

    const int g = sub >> 1;
    int rank = 0;
#pragma unroll
    for (int h = 0; h < 8; ++h) {
        float gh = __shfl(gsum, h * 2, 16);
        if (h != g && (gh > gsum || (gh == gsum && h < g))) ++rank;
    }
    const bool sel = (rank < 4);

    unsigned used = 0;
    float myoi = 0.f, myow = 0.f;
    float wsum = 0.f;
#pragma unroll
    for (int p = 0; p < 8; ++p) {
        float bv = -1e30f; int bi = 0x7fff; float bu = 0.f;
#pragma unroll
        for (int i = 0; i < 16; ++i) {
            float v = ((used >> i) & 1u) ? -1e30f : (sel ? sc[i] : 0.0f);
            if (v > bv || (v == bv && (ebase + i) < bi)) {
                bv = v; bi = ebase + i; bu = us[i];
            }
        }
#pragma unroll
        for (int d = 1; d < 16; d <<= 1) {
            float ov = __shfl_xor(bv, d, 16);
            int   oi = __shfl_xor(bi, d, 16);
            float ou = __shfl_xor(bu, d, 16);
            if (ov > bv || (ov == bv && oi < bi)) { bv = ov; bi = oi; bu = ou; }
        }
        if ((bi >> 4) == sub) used |= 1u << (bi & 15);
        if (sub == p) { myoi = (float)bi; myow = bu; }
        wsum += bu;
    }

    const float scale = 2.5f / (wsum + 1e-20f);
    if (sub < 8) {
        out[(size_t)tok * 8 + sub] = myoi;
        out[(size_t)T_TOK * 8 + (size_t)tok * 8 + sub] = myow * scale;
    }
}

// ---------------------------------------------------------------------------
extern "C" void kernel_launch(void* const* d_in, const int* in_sizes, int n_in,
                              void* d_out, int out_size, void* d_ws, size_t ws_size,
                              hipStream_t stream) {
    const float* X = (const float*)d_in[0];   // [4,4096,2048] fp32
    const float* W = (const float*)d_in[1];   // [256,2048]   fp32
    const float* B = (const float*)d_in[2];   // [256]        fp32
    float* out     = (float*)d_out;

    const size_t WE     = (size_t)E * H;                       // 524288
    const size_t planeB = WE * sizeof(unsigned short);         // 1 MB
    const size_t chunkB = (size_t)T_TOK * E * sizeof(float);   // 16 MB

    unsigned short* Wh = (unsigned short*)d_ws;
    unsigned short* Wm = Wh + WE;
    unsigned short* Wl = Wm + WE;
    float* part = (float*)((char*)d_ws + 3 * planeB);

    int nsplit = 1;
    if (ws_size >= 3 * planeB + 4 * chunkB)      nsplit = 4;
    else if (ws_size >= 3 * planeB + 2 * chunkB) nsplit = 2;
    const int klen = H / nsplit;

    prep_w<<<WE / (256 * 4), 256, 0, stream>>>(W, Wh, Wm, Wl);

    dim3 gg(E / 128, T_TOK / 128, nsplit);    // (2, 128, 4) = 1024 blocks
    gemm_logits<<<gg, 256, 0, stream>>>(X, Wh, Wm, Wl, part, klen);

    route_kernel<<<T_TOK / 16, 256, 0, stream>>>(part, B, out, nsplit);
}